// Round 1
// baseline (115.052 us; speedup 1.0000x reference)
//
#include <hip/hip_runtime.h>

// CharacterAwareEncoder:
//   out[t, 0:412]   = word_emb_table[word_ids[t], :]
//   out[t, 412:512] = sin((h/1000) * word_ids[t]),  h = 0..99, zeroed if id == 0
//
// B*S = 16*2048 = 32768 tokens, out row = 512 floats = 128 float4.
// Table row = 412 floats = 103 float4 (row byte offset 1648 is 16B aligned).
// Thread-per-float4: c4 in [0,103) -> copy, c4 in [103,128) -> sin features.

#define EMB_F4   103   // 412 floats / 4
#define ROW_F4   128   // 512 floats / 4

__global__ __launch_bounds__(256) void char_enc_kernel(
    const int*    __restrict__ word_ids,   // [32768]
    const float4* __restrict__ table4,     // [32000][103]
    float4*       __restrict__ out4,       // [32768][128]
    int total_f4)
{
    int gid = blockIdx.x * blockDim.x + threadIdx.x;
    if (gid >= total_f4) return;

    int t  = gid >> 7;    // token index
    int c4 = gid & 127;   // float4 index within output row

    int id = word_ids[t];

    if (c4 < EMB_F4) {
        // embedding gather: contiguous within a wave (each wave = half a row)
        out4[gid] = table4[(long)id * EMB_F4 + c4];
    } else {
        float4 r = make_float4(0.f, 0.f, 0.f, 0.f);
        if (id > 0) {
            int   h   = (c4 << 2) - 412;   // 0,4,...,96
            float tok = (float)id;
            // match reference order: (h/1000) computed first, then * tok
            r.x = sinf(((float)(h + 0) / 1000.0f) * tok);
            r.y = sinf(((float)(h + 1) / 1000.0f) * tok);
            r.z = sinf(((float)(h + 2) / 1000.0f) * tok);
            r.w = sinf(((float)(h + 3) / 1000.0f) * tok);
        }
        out4[gid] = r;
    }
}

extern "C" void kernel_launch(void* const* d_in, const int* in_sizes, int n_in,
                              void* d_out, int out_size, void* d_ws, size_t ws_size,
                              hipStream_t stream) {
    const int*    word_ids = (const int*)d_in[0];
    const float4* table4   = (const float4*)d_in[1];
    float4*       out4     = (float4*)d_out;

    const int n_tokens = in_sizes[0];          // 16*2048 = 32768
    const int total_f4 = n_tokens * ROW_F4;    // 4,194,304

    const int block = 256;
    const int grid  = (total_f4 + block - 1) / block;  // 16384

    char_enc_kernel<<<grid, block, 0, stream>>>(word_ids, table4, out4, total_f4);
}

// Round 3
// 114.462 us; speedup vs baseline: 1.0052x; 1.0052x over previous
//
#include <hip/hip_runtime.h>
#include <math.h>

// CharacterAwareEncoder:
//   out[t, 0:412]   = word_emb_table[word_ids[t], :]
//   out[t, 412:512] = sin((h/1000) * word_ids[t]),  h = 0..99, zeroed if id == 0
//
// B*S = 16*2048 = 32768 tokens, out row = 512 floats = 128 float4.
// Table row = 412 floats = 103 float4 (row byte offset 1648 is 16B aligned).
// Thread-per-float4: c4 in [0,103) -> copy, c4 in [103,128) -> sin features.
//
// sin args reach 32000*0.099 ~= 3168 rad: stock sinf takes the slow
// Payne-Hanek path (~hundreds of VALU insts). We range-reduce to
// REVOLUTIONS with one double mul + rint (error ~1e-16 rev), then use the
// native v_sin_f32 (__builtin_amdgcn_sinf), which takes revolutions
// directly: D = sin(S0 * 2*pi). Input rounding matches the reference
// exactly: (h/1000.0f) [fp32 divide] * (float)id.

#define EMB_F4   103   // 412 floats / 4
#define ROW_F4   128   // 512 floats / 4

__global__ __launch_bounds__(256) void char_enc_kernel(
    const int*    __restrict__ word_ids,   // [32768]
    const float4* __restrict__ table4,     // [32000][103]
    float4*       __restrict__ out4,       // [32768][128]
    int total_f4)
{
    int gid = blockIdx.x * blockDim.x + threadIdx.x;
    if (gid >= total_f4) return;

    int t  = gid >> 7;    // token index
    int c4 = gid & 127;   // float4 index within output row

    int id = word_ids[t];

    if (c4 < EMB_F4) {
        // embedding gather: each wave reads a contiguous ~1KB segment of one row
        out4[gid] = table4[(long)id * EMB_F4 + c4];
    } else {
        float4 r = make_float4(0.f, 0.f, 0.f, 0.f);
        if (id > 0) {
            int   h   = (c4 << 2) - 412;   // 0,4,...,96
            float tok = (float)id;
            const double INV_2PI = 0.15915494309189535;  // 1/(2*pi)
            float s[4];
            #pragma unroll
            for (int j = 0; j < 4; ++j) {
                // exact same fp32 rounding as the reference input
                float  a   = ((float)(h + j) / 1000.0f) * tok;
                // high-precision reduction to revolutions: frac(a / 2pi)
                double d   = (double)a * INV_2PI;
                d         -= rint(d);                    // |d| <= 0.5 rev
                // native sin: v_sin_f32 takes revolutions, D = sin(S0*2pi)
                s[j] = __builtin_amdgcn_sinf((float)d);
            }
            r.x = s[0]; r.y = s[1]; r.z = s[2]; r.w = s[3];
        }
        out4[gid] = r;
    }
}

extern "C" void kernel_launch(void* const* d_in, const int* in_sizes, int n_in,
                              void* d_out, int out_size, void* d_ws, size_t ws_size,
                              hipStream_t stream) {
    const int*    word_ids = (const int*)d_in[0];
    const float4* table4   = (const float4*)d_in[1];
    float4*       out4     = (float4*)d_out;

    const int n_tokens = in_sizes[0];          // 16*2048 = 32768
    const int total_f4 = n_tokens * ROW_F4;    // 4,194,304

    const int block = 256;
    const int grid  = (total_f4 + block - 1) / block;  // 16384

    char_enc_kernel<<<grid, block, 0, stream>>>(word_ids, table4, out4, total_f4);
}

// Round 4
// 114.073 us; speedup vs baseline: 1.0086x; 1.0034x over previous
//
#include <hip/hip_runtime.h>
#include <math.h>

// CharacterAwareEncoder:
//   out[t, 0:412]   = word_emb_table[word_ids[t], :]
//   out[t, 412:512] = sin((h/1000) * word_ids[t]),  h = 0..99, zeroed if id == 0
//
// B*S = 16*2048 = 32768 tokens, out row = 512 floats = 128 float4.
// Table row = 412 floats = 103 float4 (row byte offset 1648 is 16B aligned).
// Thread-per-float4: c4 in [0,103) -> copy, c4 in [103,128) -> sin features.
//
// R3 lesson: sin path is off the critical path (native v_sin_f32 change was
// neutral) -> memory-bound. This round attacks L2: output stores are
// NONTEMPORAL (never re-read; stop them evicting the 52.7MB gather table
// from the 4MiB/XCD L2s), and the wave-uniform token id is hoisted to SGPR
// (row = 2 waves, so t is uniform per wave) to scalarize table-base math.

#define EMB_F4   103   // 412 floats / 4
#define ROW_F4   128   // 512 floats / 4

typedef float v4f __attribute__((ext_vector_type(4)));

__global__ __launch_bounds__(256) void char_enc_kernel(
    const int* __restrict__ word_ids,   // [32768]
    const v4f* __restrict__ table4,     // [32000][103]
    v4f*       __restrict__ out4,       // [32768][128]
    int total_f4)
{
    int gid = blockIdx.x * blockDim.x + threadIdx.x;
    if (gid >= total_f4) return;   // total is multiple of 256: no partial wave

    int t  = gid >> 7;    // token index — uniform across each 64-lane wave
    int c4 = gid & 127;   // float4 index within output row

    // wave-uniform id -> SGPR (scalar 64-bit base math, frees VGPRs/VALU)
    int id = __builtin_amdgcn_readfirstlane(word_ids[t]);

    if (c4 < EMB_F4) {
        // gather: SGPR base + per-lane offset, ~1KB contiguous per wave
        v4f r = table4[(long)id * EMB_F4 + c4];
        __builtin_nontemporal_store(r, &out4[gid]);
    } else {
        v4f r = (v4f)0.0f;
        if (id > 0) {
            int   h   = (c4 << 2) - 412;   // 0,4,...,96
            float tok = (float)id;
            const double INV_2PI = 0.15915494309189535;  // 1/(2*pi)
            #pragma unroll
            for (int j = 0; j < 4; ++j) {
                // exact same fp32 input rounding as the reference
                float  a = ((float)(h + j) / 1000.0f) * tok;
                // high-precision reduction to revolutions: frac(a / 2pi)
                double d = (double)a * INV_2PI;
                d       -= rint(d);                    // |d| <= 0.5 rev
                // native v_sin_f32 takes revolutions: D = sin(S0*2pi)
                r[j] = __builtin_amdgcn_sinf((float)d);
            }
        }
        __builtin_nontemporal_store(r, &out4[gid]);
    }
}

extern "C" void kernel_launch(void* const* d_in, const int* in_sizes, int n_in,
                              void* d_out, int out_size, void* d_ws, size_t ws_size,
                              hipStream_t stream) {
    const int* word_ids = (const int*)d_in[0];
    const v4f* table4   = (const v4f*)d_in[1];
    v4f*       out4     = (v4f*)d_out;

    const int n_tokens = in_sizes[0];          // 16*2048 = 32768
    const int total_f4 = n_tokens * ROW_F4;    // 4,194,304

    const int block = 256;
    const int grid  = (total_f4 + block - 1) / block;  // 16384

    char_enc_kernel<<<grid, block, 0, stream>>>(word_ids, table4, out4, total_f4);
}